// Round 11
// baseline (351.705 us; speedup 1.0000x reference)
//
#include <hip/hip_runtime.h>

typedef unsigned short u16;
typedef __attribute__((ext_vector_type(8))) short short8;
typedef __attribute__((ext_vector_type(4))) short short4v;
typedef __attribute__((ext_vector_type(4))) float f32x4;

#define S_LEN 2048
#define EMB   1024
#define NH    16
#define NEGM  (-1e10f)

__device__ __forceinline__ u16 f2bf(float f) {
  unsigned u = __float_as_uint(f);
  u += 0x7fffu + ((u >> 16) & 1u);
  return (u16)(u >> 16);
}

__device__ __forceinline__ void async16(const u16* g, u16* l) {
  __builtin_amdgcn_global_load_lds(
      (const __attribute__((address_space(1))) unsigned int*)g,
      (__attribute__((address_space(3))) unsigned int*)l, 16, 0, 0);
}

// ---------------- fused cast fp32 -> bf16 for 3 arrays ----------------
__global__ __launch_bounds__(256) void cast3_kernel(
    const float* __restrict__ a, u16* __restrict__ oa, int na,
    const float* __restrict__ b, u16* __restrict__ ob, int nb,
    const float* __restrict__ c, u16* __restrict__ oc, int nc) {
  int t = (blockIdx.x * 256 + threadIdx.x) * 8;
  const float* in;
  u16* out;
  if (t < na) { in = a + t; out = oa + t; }
  else if (t < na + nb) { in = b + (t - na); out = ob + (t - na); }
  else if (t < na + nb + nc) { in = c + (t - na - nb); out = oc + (t - na - nb); }
  else return;
  f32x4 lo = *(const f32x4*)(in);
  f32x4 hi = *(const f32x4*)(in + 4);
  u16 r[8];
  r[0] = f2bf(lo.x); r[1] = f2bf(lo.y); r[2] = f2bf(lo.z); r[3] = f2bf(lo.w);
  r[4] = f2bf(hi.x); r[5] = f2bf(hi.y); r[6] = f2bf(hi.z); r[7] = f2bf(hi.w);
  *(short8*)(out) = *(short8*)r;
}

// ---------------- bf16 GEMM: C[M,N] = A[M,K] * B[N,K]^T + bias ----------------
// BMxBN tile, BK=64, 4 waves (2x2).
template <int BM, int BN, int OUT_BF16>
__global__ __launch_bounds__(256, 2) void gemm_kernel(
    const u16* __restrict__ A, const u16* __restrict__ B,
    const float* __restrict__ bias, void* __restrict__ Cout,
    int M, int N, int K, int grid_x) {
  __shared__ u16 As[BM * 64];
  __shared__ u16 Bs[BN * 64];
  const int b = blockIdx.x;
  const int tid = threadIdx.x;
  const int lane = tid & 63, wave = tid >> 6;
  const int lr = lane & 15, lg = lane >> 4;
  const int bx = b % grid_x, by = b / grid_x;
  const int m0 = by * BM, n0 = bx * BN;
  const int wm = (wave >> 1) * (BM / 2), wn = (wave & 1) * (BN / 2);
  constexpr int MI = BM / 32, NJ = BN / 32;

  f32x4 acc[MI][NJ];
#pragma unroll
  for (int i = 0; i < MI; ++i)
#pragma unroll
    for (int j = 0; j < NJ; ++j) acc[i][j] = (f32x4){0.f, 0.f, 0.f, 0.f};

  for (int kt = 0; kt < K; kt += 64) {
#pragma unroll
    for (int it = 0; it < BM / 32; ++it) {
      int f = it * 256 + tid;
      int row = f >> 3, ch = f & 7;
      int sch = ch ^ (row & 7);  // inverse-swizzle the global SOURCE
      async16(A + (size_t)(m0 + row) * K + kt + sch * 8,
              &As[(it * 256 + wave * 64) * 8]);
    }
#pragma unroll
    for (int it = 0; it < BN / 32; ++it) {
      int f = it * 256 + tid;
      int row = f >> 3, ch = f & 7;
      int sch = ch ^ (row & 7);
      async16(B + (size_t)(n0 + row) * K + kt + sch * 8,
              &Bs[(it * 256 + wave * 64) * 8]);
    }
    __syncthreads();
#pragma unroll
    for (int kk = 0; kk < 2; ++kk) {
      short8 af[MI], bfr[NJ];
      int ca = kk * 4 + lg;
#pragma unroll
      for (int t = 0; t < MI; ++t) {
        int ra = wm + t * 16 + lr;
        af[t] = *(const short8*)&As[ra * 64 + ((ca ^ (ra & 7)) << 3)];
      }
#pragma unroll
      for (int t = 0; t < NJ; ++t) {
        int rb = wn + t * 16 + lr;
        bfr[t] = *(const short8*)&Bs[rb * 64 + ((ca ^ (rb & 7)) << 3)];
      }
#pragma unroll
      for (int i = 0; i < MI; ++i)
#pragma unroll
        for (int j = 0; j < NJ; ++j)
          acc[i][j] = __builtin_amdgcn_mfma_f32_16x16x32_bf16(af[i], bfr[j],
                                                              acc[i][j], 0, 0, 0);
    }
    __syncthreads();
  }
  // epilogue: D layout col=lane&15, row=(lane>>4)*4+reg
#pragma unroll
  for (int j = 0; j < NJ; ++j) {
    int col = n0 + wn + j * 16 + lr;
    float bv = bias[col];
#pragma unroll
    for (int i = 0; i < MI; ++i) {
#pragma unroll
      for (int r = 0; r < 4; ++r) {
        int row = m0 + wm + i * 16 + lg * 4 + r;
        float v = acc[i][j][r] + bv;
        if (OUT_BF16)
          ((u16*)Cout)[(size_t)row * N + col] = f2bf(v);
        else
          ((float*)Cout)[(size_t)row * N + col] = v;
      }
    }
  }
}

// ---------------- fused banded attention (writes ALL scores cells) ----
// grid: (32 query-tiles of 64, 16 heads), 256 threads (4 waves).
// Wave w owns query rows [i0+16w, i0+16w+16). Key window: [i0-64, i0+128).
// Out-of-window cells are NEGM-filled HERE with coalesced NT f4 spans
// (no separate fill kernel; every scores cell written exactly once).
__global__ __launch_bounds__(256, 2) void attn_kernel(
    const u16* __restrict__ qkv,   // [2048][3072] bf16
    float* __restrict__ scores,    // [16][2048][2048] fp32
    u16* __restrict__ ctx) {       // [2048][1024] bf16
  const int h = blockIdx.y;
  const int i0 = blockIdx.x * 64;
  const int j0 = i0 - 64;
  const int tid = threadIdx.x;
  const int lane = tid & 63, wave = tid >> 6;
  const int lr = lane & 15, lg = lane >> 4;

  __shared__ u16 Kl[192 * 72];   // K tile, stride 72 -> 2-way conflicts max
  __shared__ u16 Vt[64 * 200];   // V^T tile [d][jr]
  __shared__ u16 Pl[64 * 200];   // probs bf16 [qi][jr]

  // ---- stage K and V^T (zero-fill out-of-range keys) ----
#pragma unroll
  for (int it = 0; it < 6; ++it) {
    int f = it * 256 + tid;      // 0..1535
    int jr = f >> 3, ch = f & 7;
    int j = j0 + jr;
    short8 kv = {0, 0, 0, 0, 0, 0, 0, 0};
    short8 vv = {0, 0, 0, 0, 0, 0, 0, 0};
    if ((unsigned)j < 2048u) {
      kv = *(const short8*)(qkv + (size_t)j * 3072 + 1024 + h * 64 + ch * 8);
      vv = *(const short8*)(qkv + (size_t)j * 3072 + 2048 + h * 64 + ch * 8);
    }
    *(short4v*)&Kl[jr * 72 + ch * 8] = __builtin_shufflevector(kv, kv, 0, 1, 2, 3);
    *(short4v*)&Kl[jr * 72 + ch * 8 + 4] = __builtin_shufflevector(kv, kv, 4, 5, 6, 7);
#pragma unroll
    for (int e = 0; e < 8; ++e) Vt[(ch * 8 + e) * 200 + jr] = (u16)(short)vv[e];
  }
  __syncthreads();

  // ---- Q fragments straight from global (L2-hot) ----
  short8 qf[2];
#pragma unroll
  for (int kk = 0; kk < 2; ++kk)
    qf[kk] = *(const short8*)(qkv + (size_t)(i0 + wave * 16 + lr) * 3072 +
                              h * 64 + kk * 32 + lg * 8);

  // ---- QK^T: 12 col-tiles of 16, 2 k-substeps ----
  f32x4 sa[12];
#pragma unroll
  for (int n = 0; n < 12; ++n) sa[n] = (f32x4){0.f, 0.f, 0.f, 0.f};
#pragma unroll
  for (int kk = 0; kk < 2; ++kk) {
    short8 a = qf[kk];
#pragma unroll
    for (int nt = 0; nt < 12; ++nt) {
      int jr = nt * 16 + lr;
      int d = kk * 32 + lg * 8;
      short4v lo = *(const short4v*)&Kl[jr * 72 + d];
      short4v hi = *(const short4v*)&Kl[jr * 72 + d + 4];
      short8 b = __builtin_shufflevector(lo, hi, 0, 1, 2, 3, 4, 5, 6, 7);
      sa[nt] = __builtin_amdgcn_mfma_f32_16x16x32_bf16(a, b, sa[nt], 0, 0, 0);
    }
  }

  // ---- scale + band mask (in place) ----
  const float scale = 0.125f;  // DH^-0.5
#pragma unroll
  for (int nt = 0; nt < 12; ++nt) {
    int j = j0 + nt * 16 + lr;
#pragma unroll
    for (int r = 0; r < 4; ++r) {
      int i = i0 + wave * 16 + lg * 4 + r;
      bool inb = (j >= i - 64) && (j <= i + 64);
      sa[nt][r] = inb ? sa[nt][r] * scale : NEGM;
    }
  }

  // ---- write the valid window (cached scalar stores) ----
  float* srow_base = scores + (size_t)h * 2048 * 2048;
#pragma unroll
  for (int r = 0; r < 4; ++r) {
    int i = i0 + wave * 16 + lg * 4 + r;
    float* rowp = srow_base + (size_t)i * 2048;
#pragma unroll
    for (int nt = 0; nt < 12; ++nt) {
      int j = j0 + nt * 16 + lr;
      if ((unsigned)j < 2048u) rowp[j] = sa[nt][r];
    }
  }

  // ---- softmax per row (16-lane group holds a full 192-col row) ----
#pragma unroll
  for (int r = 0; r < 4; ++r) {
    float m = sa[0][r];
#pragma unroll
    for (int nt = 1; nt < 12; ++nt) m = fmaxf(m, sa[nt][r]);
#pragma unroll
    for (int off = 1; off < 16; off <<= 1) m = fmaxf(m, __shfl_xor(m, off));
    float p[12], s = 0.f;
#pragma unroll
    for (int nt = 0; nt < 12; ++nt) {
      p[nt] = __expf(sa[nt][r] - m);  // masked -> 0
      s += p[nt];
    }
#pragma unroll
    for (int off = 1; off < 16; off <<= 1) s += __shfl_xor(s, off);
    float inv = 1.f / s;
    int row = wave * 16 + lg * 4 + r;
#pragma unroll
    for (int nt = 0; nt < 12; ++nt)
      Pl[row * 200 + nt * 16 + lr] = f2bf(p[nt] * inv);
  }
  __syncthreads();

  // ---- PV: ctx[64][64] = P[64][192] @ V[192][64] ----
  f32x4 ca[4];
#pragma unroll
  for (int d = 0; d < 4; ++d) ca[d] = (f32x4){0.f, 0.f, 0.f, 0.f};
#pragma unroll
  for (int kk = 0; kk < 6; ++kk) {
    short8 a = *(const short8*)&Pl[(wave * 16 + lr) * 200 + kk * 32 + lg * 8];
#pragma unroll
    for (int dt = 0; dt < 4; ++dt) {
      short8 b = *(const short8*)&Vt[(dt * 16 + lr) * 200 + kk * 32 + lg * 8];
      ca[dt] = __builtin_amdgcn_mfma_f32_16x16x32_bf16(a, b, ca[dt], 0, 0, 0);
    }
  }
#pragma unroll
  for (int dt = 0; dt < 4; ++dt)
#pragma unroll
    for (int r = 0; r < 4; ++r) {
      int i = i0 + wave * 16 + lg * 4 + r;
      int d = h * 64 + dt * 16 + lr;
      ctx[(size_t)i * 1024 + d] = f2bf(ca[dt][r]);
    }

  // ---- NEGM-fill all out-of-window scores cells for this block's rows.
  // Window [lw, rw) is block-uniform and 64-aligned -> f4-aligned spans.
  {
    const int lw = (j0 > 0) ? j0 : 0;
    const int rw = (j0 + 192 < 2048) ? (j0 + 192) : 2048;
    const int nl = lw >> 2;            // f4 count, left span [0, lw)
    const int nr = (2048 - rw) >> 2;   // f4 count, right span [rw, 2048)
    const f32x4 neg = {NEGM, NEGM, NEGM, NEGM};
    for (int r = 0; r < 64; ++r) {
      f32x4* rowp = (f32x4*)(srow_base + (size_t)(i0 + r) * 2048);
      for (int c = tid; c < nl; c += 256)
        __builtin_nontemporal_store(neg, rowp + c);
      f32x4* rowr = rowp + (rw >> 2);
      for (int c = tid; c < nr; c += 256)
        __builtin_nontemporal_store(neg, rowr + c);
    }
  }
}

// ---------------- launcher ----------------
extern "C" void kernel_launch(void* const* d_in, const int* in_sizes, int n_in,
                              void* d_out, int out_size, void* d_ws, size_t ws_size,
                              hipStream_t stream) {
  const float* x    = (const float*)d_in[0];
  const float* Wqkv = (const float*)d_in[1];
  const float* bqkv = (const float*)d_in[2];
  const float* Wout = (const float*)d_in[3];
  const float* bout = (const float*)d_in[4];

  float* out    = (float*)d_out;
  float* scores = out + (size_t)S_LEN * EMB;

  char* ws = (char*)d_ws;
  u16* x_bf    = (u16*)(ws);
  u16* wqkv_bf = (u16*)(ws + (4u << 20));
  u16* wout_bf = (u16*)(ws + (10u << 20));
  u16* qkv_bf  = (u16*)(ws + (12u << 20));
  u16* ctx_bf  = (u16*)(ws + (24u << 20));

  const int n1 = S_LEN * EMB;       // x
  const int n2 = 3 * EMB * EMB;     // W_qkv
  const int n3 = EMB * EMB;         // W_out

  // all three casts in one launch
  cast3_kernel<<<(n1 + n2 + n3) / 8 / 256, 256, 0, stream>>>(
      x, x_bf, n1, Wqkv, wqkv_bf, n2, Wout, wout_bf, n3);

  // qkv = x @ Wqkv^T + b (bf16 out); pure GEMM, full machine
  gemm_kernel<128, 128, 1><<<dim3(384), 256, 0, stream>>>(
      x_bf, wqkv_bf, bqkv, qkv_bf, S_LEN, 3 * EMB, EMB,
      /*grid_x=*/3 * EMB / 128);

  // banded attention: writes band + NEGM fill (all scores cells), writes ctx
  attn_kernel<<<dim3(S_LEN / 64, NH), 256, 0, stream>>>(qkv_bf, scores, ctx_bf);

  // out = ctx @ Wout^T + b (fp32 out); 64x128 tiles -> 256 blocks = 1/CU
  gemm_kernel<64, 128, 0><<<dim3(256), 256, 0, stream>>>(
      ctx_bf, wout_bf, bout, out, S_LEN, EMB, EMB,
      /*grid_x=*/EMB / 128);
}

// Round 12
// 324.406 us; speedup vs baseline: 1.0842x; 1.0842x over previous
//
#include <hip/hip_runtime.h>

typedef unsigned short u16;
typedef __attribute__((ext_vector_type(8))) short short8;
typedef __attribute__((ext_vector_type(4))) short short4v;
typedef __attribute__((ext_vector_type(4))) float f32x4;

#define S_LEN 2048
#define EMB   1024
#define NH    16
#define NEGM  (-1e10f)
#define NROWS (NH * S_LEN)        // 32768 flattened score rows
#define RSPLIT 20480              // rows [0,RSPLIT) linear-filled with GEMM1;
                                  // rows [RSPLIT,32768) complement-filled with GEMM2

__device__ __forceinline__ u16 f2bf(float f) {
  unsigned u = __float_as_uint(f);
  u += 0x7fffu + ((u >> 16) & 1u);
  return (u16)(u >> 16);
}

__device__ __forceinline__ void async16(const u16* g, u16* l) {
  __builtin_amdgcn_global_load_lds(
      (const __attribute__((address_space(1))) unsigned int*)g,
      (__attribute__((address_space(3))) unsigned int*)l, 16, 0, 0);
}

// ---------------- fused cast fp32 -> bf16 for 3 arrays ----------------
__global__ __launch_bounds__(256) void cast3_kernel(
    const float* __restrict__ a, u16* __restrict__ oa, int na,
    const float* __restrict__ b, u16* __restrict__ ob, int nb,
    const float* __restrict__ c, u16* __restrict__ oc, int nc) {
  int t = (blockIdx.x * 256 + threadIdx.x) * 8;
  const float* in;
  u16* out;
  if (t < na) { in = a + t; out = oa + t; }
  else if (t < na + nb) { in = b + (t - na); out = ob + (t - na); }
  else if (t < na + nb + nc) { in = c + (t - na - nb); out = oc + (t - na - nb); }
  else return;
  f32x4 lo = *(const f32x4*)(in);
  f32x4 hi = *(const f32x4*)(in + 4);
  u16 r[8];
  r[0] = f2bf(lo.x); r[1] = f2bf(lo.y); r[2] = f2bf(lo.z); r[3] = f2bf(lo.w);
  r[4] = f2bf(hi.x); r[5] = f2bf(hi.y); r[6] = f2bf(hi.z); r[7] = f2bf(hi.w);
  *(short8*)(out) = *(short8*)r;
}

// ---------------- bf16 GEMM: C[M,N] = A[M,K] * B[N,K]^T + bias ----------------
// BMxBN tile, BK=64, 4 waves (2x2). Blocks b >= gemm_blocks are fill blocks:
//   fill_mode 0: linear NT NEGM fill of fill_f4 f32x4's at fill_ptr
//   fill_mode 1: band-COMPLEMENT NEGM fill for flattened rows [fill_f4, NROWS)
//                (fill_f4 reused as row-split; skips attn's 192-col window)
template <int BM, int BN, int OUT_BF16, int MINW>
__global__ __launch_bounds__(256, MINW) void gemm_kernel(
    const u16* __restrict__ A, const u16* __restrict__ B,
    const float* __restrict__ bias, void* __restrict__ Cout,
    int M, int N, int K, int grid_x, int gemm_blocks,
    float* __restrict__ fill_ptr, long long fill_f4, int fill_blocks,
    int fill_mode) {
  __shared__ u16 As[BM * 64];
  __shared__ u16 Bs[BN * 64];
  const int b = blockIdx.x;
  const int tid = threadIdx.x;

  if (b >= gemm_blocks) {
    const int fb = b - gemm_blocks;
    const f32x4 neg = {NEGM, NEGM, NEGM, NEGM};
    if (fill_mode == 0) {       // linear streaming fill
      f32x4* p = (f32x4*)fill_ptr;
      const long long stride = (long long)fill_blocks * 256;
      for (long long idx = (long long)fb * 256 + tid; idx < fill_f4; idx += stride)
        __builtin_nontemporal_store(neg, p + idx);
    } else {                    // band-complement fill, rows [fill_f4, NROWS)
      for (int R = (int)fill_f4 + fb; R < NROWS; R += fill_blocks) {
        int i  = R & (S_LEN - 1);
        int i0 = i & ~63;
        int lw = (i0 - 64 > 0) ? i0 - 64 : 0;
        int rw = (i0 + 128 < S_LEN) ? i0 + 128 : S_LEN;
        f32x4* rowp = (f32x4*)(fill_ptr + (size_t)R * S_LEN);
        const int nl = lw >> 2, nr = (S_LEN - rw) >> 2;
        for (int c = tid; c < nl; c += 256)
          __builtin_nontemporal_store(neg, rowp + c);
        f32x4* rowr = rowp + (rw >> 2);
        for (int c = tid; c < nr; c += 256)
          __builtin_nontemporal_store(neg, rowr + c);
      }
    }
    return;
  }

  const int lane = tid & 63, wave = tid >> 6;
  const int lr = lane & 15, lg = lane >> 4;
  const int bx = b % grid_x, by = b / grid_x;
  const int m0 = by * BM, n0 = bx * BN;
  const int wm = (wave >> 1) * (BM / 2), wn = (wave & 1) * (BN / 2);
  constexpr int MI = BM / 32, NJ = BN / 32;

  f32x4 acc[MI][NJ];
#pragma unroll
  for (int i = 0; i < MI; ++i)
#pragma unroll
    for (int j = 0; j < NJ; ++j) acc[i][j] = (f32x4){0.f, 0.f, 0.f, 0.f};

  for (int kt = 0; kt < K; kt += 64) {
#pragma unroll
    for (int it = 0; it < BM / 32; ++it) {
      int f = it * 256 + tid;
      int row = f >> 3, ch = f & 7;
      int sch = ch ^ (row & 7);  // inverse-swizzle the global SOURCE
      async16(A + (size_t)(m0 + row) * K + kt + sch * 8,
              &As[(it * 256 + wave * 64) * 8]);
    }
#pragma unroll
    for (int it = 0; it < BN / 32; ++it) {
      int f = it * 256 + tid;
      int row = f >> 3, ch = f & 7;
      int sch = ch ^ (row & 7);
      async16(B + (size_t)(n0 + row) * K + kt + sch * 8,
              &Bs[(it * 256 + wave * 64) * 8]);
    }
    __syncthreads();
#pragma unroll
    for (int kk = 0; kk < 2; ++kk) {
      short8 af[MI], bfr[NJ];
      int ca = kk * 4 + lg;
#pragma unroll
      for (int t = 0; t < MI; ++t) {
        int ra = wm + t * 16 + lr;
        af[t] = *(const short8*)&As[ra * 64 + ((ca ^ (ra & 7)) << 3)];
      }
#pragma unroll
      for (int t = 0; t < NJ; ++t) {
        int rb = wn + t * 16 + lr;
        bfr[t] = *(const short8*)&Bs[rb * 64 + ((ca ^ (rb & 7)) << 3)];
      }
#pragma unroll
      for (int i = 0; i < MI; ++i)
#pragma unroll
        for (int j = 0; j < NJ; ++j)
          acc[i][j] = __builtin_amdgcn_mfma_f32_16x16x32_bf16(af[i], bfr[j],
                                                              acc[i][j], 0, 0, 0);
    }
    __syncthreads();
  }
  // epilogue: D layout col=lane&15, row=(lane>>4)*4+reg
#pragma unroll
  for (int j = 0; j < NJ; ++j) {
    int col = n0 + wn + j * 16 + lr;
    float bv = bias[col];
#pragma unroll
    for (int i = 0; i < MI; ++i) {
#pragma unroll
      for (int r = 0; r < 4; ++r) {
        int row = m0 + wm + i * 16 + lg * 4 + r;
        float v = acc[i][j][r] + bv;
        if (OUT_BF16)
          ((u16*)Cout)[(size_t)row * N + col] = f2bf(v);
        else
          ((float*)Cout)[(size_t)row * N + col] = v;
      }
    }
  }
}

// ---------------- fused banded attention (band window writes only) ----
// grid: (32 query-tiles of 64, 16 heads), 256 threads (4 waves).
// Wave w owns query rows [i0+16w, i0+16w+16). Key window: [i0-64, i0+128).
__global__ __launch_bounds__(256, 2) void attn_kernel(
    const u16* __restrict__ qkv,   // [2048][3072] bf16
    float* __restrict__ scores,    // [16][2048][2048] fp32
    u16* __restrict__ ctx) {       // [2048][1024] bf16
  const int h = blockIdx.y;
  const int i0 = blockIdx.x * 64;
  const int j0 = i0 - 64;
  const int tid = threadIdx.x;
  const int lane = tid & 63, wave = tid >> 6;
  const int lr = lane & 15, lg = lane >> 4;

  __shared__ u16 Kl[192 * 72];   // K tile, stride 72 -> 2-way conflicts max
  __shared__ u16 Vt[64 * 200];   // V^T tile [d][jr]
  __shared__ u16 Pl[64 * 200];   // probs bf16 [qi][jr]

  // ---- stage K and V^T (zero-fill out-of-range keys) ----
#pragma unroll
  for (int it = 0; it < 6; ++it) {
    int f = it * 256 + tid;      // 0..1535
    int jr = f >> 3, ch = f & 7;
    int j = j0 + jr;
    short8 kv = {0, 0, 0, 0, 0, 0, 0, 0};
    short8 vv = {0, 0, 0, 0, 0, 0, 0, 0};
    if ((unsigned)j < 2048u) {
      kv = *(const short8*)(qkv + (size_t)j * 3072 + 1024 + h * 64 + ch * 8);
      vv = *(const short8*)(qkv + (size_t)j * 3072 + 2048 + h * 64 + ch * 8);
    }
    *(short4v*)&Kl[jr * 72 + ch * 8] = __builtin_shufflevector(kv, kv, 0, 1, 2, 3);
    *(short4v*)&Kl[jr * 72 + ch * 8 + 4] = __builtin_shufflevector(kv, kv, 4, 5, 6, 7);
#pragma unroll
    for (int e = 0; e < 8; ++e) Vt[(ch * 8 + e) * 200 + jr] = (u16)(short)vv[e];
  }
  __syncthreads();

  // ---- Q fragments straight from global (L2-hot) ----
  short8 qf[2];
#pragma unroll
  for (int kk = 0; kk < 2; ++kk)
    qf[kk] = *(const short8*)(qkv + (size_t)(i0 + wave * 16 + lr) * 3072 +
                              h * 64 + kk * 32 + lg * 8);

  // ---- QK^T: 12 col-tiles of 16, 2 k-substeps ----
  f32x4 sa[12];
#pragma unroll
  for (int n = 0; n < 12; ++n) sa[n] = (f32x4){0.f, 0.f, 0.f, 0.f};
#pragma unroll
  for (int kk = 0; kk < 2; ++kk) {
    short8 a = qf[kk];
#pragma unroll
    for (int nt = 0; nt < 12; ++nt) {
      int jr = nt * 16 + lr;
      int d = kk * 32 + lg * 8;
      short4v lo = *(const short4v*)&Kl[jr * 72 + d];
      short4v hi = *(const short4v*)&Kl[jr * 72 + d + 4];
      short8 b = __builtin_shufflevector(lo, hi, 0, 1, 2, 3, 4, 5, 6, 7);
      sa[nt] = __builtin_amdgcn_mfma_f32_16x16x32_bf16(a, b, sa[nt], 0, 0, 0);
    }
  }

  // ---- scale + band mask (in place) ----
  const float scale = 0.125f;  // DH^-0.5
#pragma unroll
  for (int nt = 0; nt < 12; ++nt) {
    int j = j0 + nt * 16 + lr;
#pragma unroll
    for (int r = 0; r < 4; ++r) {
      int i = i0 + wave * 16 + lg * 4 + r;
      bool inb = (j >= i - 64) && (j <= i + 64);
      sa[nt][r] = inb ? sa[nt][r] * scale : NEGM;
    }
  }

  // ---- write the valid window (cached scalar stores) ----
  float* srow_base = scores + (size_t)h * 2048 * 2048;
#pragma unroll
  for (int r = 0; r < 4; ++r) {
    int i = i0 + wave * 16 + lg * 4 + r;
    float* rowp = srow_base + (size_t)i * 2048;
#pragma unroll
    for (int nt = 0; nt < 12; ++nt) {
      int j = j0 + nt * 16 + lr;
      if ((unsigned)j < 2048u) rowp[j] = sa[nt][r];
    }
  }

  // ---- softmax per row (16-lane group holds a full 192-col row) ----
#pragma unroll
  for (int r = 0; r < 4; ++r) {
    float m = sa[0][r];
#pragma unroll
    for (int nt = 1; nt < 12; ++nt) m = fmaxf(m, sa[nt][r]);
#pragma unroll
    for (int off = 1; off < 16; off <<= 1) m = fmaxf(m, __shfl_xor(m, off));
    float p[12], s = 0.f;
#pragma unroll
    for (int nt = 0; nt < 12; ++nt) {
      p[nt] = __expf(sa[nt][r] - m);  // masked -> 0
      s += p[nt];
    }
#pragma unroll
    for (int off = 1; off < 16; off <<= 1) s += __shfl_xor(s, off);
    float inv = 1.f / s;
    int row = wave * 16 + lg * 4 + r;
#pragma unroll
    for (int nt = 0; nt < 12; ++nt)
      Pl[row * 200 + nt * 16 + lr] = f2bf(p[nt] * inv);
  }
  __syncthreads();

  // ---- PV: ctx[64][64] = P[64][192] @ V[192][64] ----
  f32x4 ca[4];
#pragma unroll
  for (int d = 0; d < 4; ++d) ca[d] = (f32x4){0.f, 0.f, 0.f, 0.f};
#pragma unroll
  for (int kk = 0; kk < 6; ++kk) {
    short8 a = *(const short8*)&Pl[(wave * 16 + lr) * 200 + kk * 32 + lg * 8];
#pragma unroll
    for (int dt = 0; dt < 4; ++dt) {
      short8 b = *(const short8*)&Vt[(dt * 16 + lr) * 200 + kk * 32 + lg * 8];
      ca[dt] = __builtin_amdgcn_mfma_f32_16x16x32_bf16(a, b, ca[dt], 0, 0, 0);
    }
  }
#pragma unroll
  for (int dt = 0; dt < 4; ++dt)
#pragma unroll
    for (int r = 0; r < 4; ++r) {
      int i = i0 + wave * 16 + lg * 4 + r;
      int d = h * 64 + dt * 16 + lr;
      ctx[(size_t)i * 1024 + d] = f2bf(ca[dt][r]);
    }
}

// ---------------- launcher ----------------
extern "C" void kernel_launch(void* const* d_in, const int* in_sizes, int n_in,
                              void* d_out, int out_size, void* d_ws, size_t ws_size,
                              hipStream_t stream) {
  const float* x    = (const float*)d_in[0];
  const float* Wqkv = (const float*)d_in[1];
  const float* bqkv = (const float*)d_in[2];
  const float* Wout = (const float*)d_in[3];
  const float* bout = (const float*)d_in[4];

  float* out    = (float*)d_out;
  float* scores = out + (size_t)S_LEN * EMB;

  char* ws = (char*)d_ws;
  u16* x_bf    = (u16*)(ws);
  u16* wqkv_bf = (u16*)(ws + (4u << 20));
  u16* wout_bf = (u16*)(ws + (10u << 20));
  u16* qkv_bf  = (u16*)(ws + (12u << 20));
  u16* ctx_bf  = (u16*)(ws + (24u << 20));

  const int n1 = S_LEN * EMB;       // x
  const int n2 = 3 * EMB * EMB;     // W_qkv
  const int n3 = EMB * EMB;         // W_out

  // all three casts in one launch
  cast3_kernel<<<(n1 + n2 + n3) / 8 / 256, 256, 0, stream>>>(
      x, x_bf, n1, Wqkv, wqkv_bf, n2, Wout, wout_bf, n3);

  // qkv = x @ Wqkv^T + b (bf16 out), co-launched with linear NEGM fill of
  // score rows [0, RSPLIT). 384 GEMM + 384 fill blocks, 3 blocks/CU.
  gemm_kernel<128, 128, 1, 3><<<768, 256, 0, stream>>>(
      x_bf, wqkv_bf, bqkv, qkv_bf, S_LEN, 3 * EMB, EMB,
      /*grid_x=*/3 * EMB / 128, /*gemm_blocks=*/384,
      scores, (long long)RSPLIT * (S_LEN / 4), /*fill_blocks=*/384,
      /*fill_mode=*/0);

  // banded attention: writes band window + ctx
  attn_kernel<<<dim3(S_LEN / 64, NH), 256, 0, stream>>>(qkv_bf, scores, ctx_bf);

  // out = ctx @ Wout^T + b (fp32 out); 64x64 tiles -> 512 blocks (2/CU),
  // co-launched with band-COMPLEMENT fill of score rows [RSPLIT, 32768)
  // (disjoint from the band attn wrote, so ordering is safe).
  gemm_kernel<64, 64, 0, 3><<<768, 256, 0, stream>>>(
      ctx_bf, wout_bf, bout, out, S_LEN, EMB, EMB,
      /*grid_x=*/EMB / 64, /*gemm_blocks=*/512,
      scores, (long long)RSPLIT, /*fill_blocks=*/256,
      /*fill_mode=*/1);
}

// Round 13
// 322.136 us; speedup vs baseline: 1.0918x; 1.0070x over previous
//
#include <hip/hip_runtime.h>

typedef unsigned short u16;
typedef __attribute__((ext_vector_type(8))) short short8;
typedef __attribute__((ext_vector_type(4))) short short4v;
typedef __attribute__((ext_vector_type(4))) float f32x4;

#define S_LEN 2048
#define EMB   1024
#define NH    16
#define NEGM  (-1e10f)
#define NROWS (NH * S_LEN)        // 32768 flattened score rows
#define RSPLIT 20480              // rows [0,RSPLIT) filled with GEMM1 phase;
                                  // rows [RSPLIT,32768) filled with GEMM2 phase

__device__ __forceinline__ u16 f2bf(float f) {
  unsigned u = __float_as_uint(f);
  u += 0x7fffu + ((u >> 16) & 1u);
  return (u16)(u >> 16);
}

__device__ __forceinline__ void async16(const u16* g, u16* l) {
  __builtin_amdgcn_global_load_lds(
      (const __attribute__((address_space(1))) unsigned int*)g,
      (__attribute__((address_space(3))) unsigned int*)l, 16, 0, 0);
}

// ---------------- fused cast fp32 -> bf16 for 3 arrays ----------------
__global__ __launch_bounds__(256) void cast3_kernel(
    const float* __restrict__ a, u16* __restrict__ oa, int na,
    const float* __restrict__ b, u16* __restrict__ ob, int nb,
    const float* __restrict__ c, u16* __restrict__ oc, int nc) {
  int t = (blockIdx.x * 256 + threadIdx.x) * 8;
  const float* in;
  u16* out;
  if (t < na) { in = a + t; out = oa + t; }
  else if (t < na + nb) { in = b + (t - na); out = ob + (t - na); }
  else if (t < na + nb + nc) { in = c + (t - na - nb); out = oc + (t - na - nb); }
  else return;
  f32x4 lo = *(const f32x4*)(in);
  f32x4 hi = *(const f32x4*)(in + 4);
  u16 r[8];
  r[0] = f2bf(lo.x); r[1] = f2bf(lo.y); r[2] = f2bf(lo.z); r[3] = f2bf(lo.w);
  r[4] = f2bf(hi.x); r[5] = f2bf(hi.y); r[6] = f2bf(hi.z); r[7] = f2bf(hi.w);
  *(short8*)(out) = *(short8*)r;
}

// ---------------- bf16 GEMM: C[M,N] = A[M,K] * B[N,K]^T + bias ----------------
// BMxBN tile, BK=64, 4 waves (2x2). Blocks b >= gemm_blocks are fill blocks:
// band-COMPLEMENT NEGM fill for flattened score rows [fr0, fr1) — writes only
// the out-of-window spans (window is block-uniform, 64-aligned -> f4 spans).
template <int BM, int BN, int OUT_BF16, int MINW>
__global__ __launch_bounds__(256, MINW) void gemm_kernel(
    const u16* __restrict__ A, const u16* __restrict__ B,
    const float* __restrict__ bias, void* __restrict__ Cout,
    int M, int N, int K, int grid_x, int gemm_blocks,
    float* __restrict__ fill_ptr, int fr0, int fr1, int fill_blocks) {
  __shared__ u16 As[BM * 64];
  __shared__ u16 Bs[BN * 64];
  const int b = blockIdx.x;
  const int tid = threadIdx.x;

  if (b >= gemm_blocks) {  // ---- band-complement NEGM fill ----
    const int fb = b - gemm_blocks;
    const f32x4 neg = {NEGM, NEGM, NEGM, NEGM};
    for (int R = fr0 + fb; R < fr1; R += fill_blocks) {
      int i  = R & (S_LEN - 1);
      int i0 = i & ~63;
      int lw = (i0 - 64 > 0) ? i0 - 64 : 0;
      int rw = (i0 + 128 < S_LEN) ? i0 + 128 : S_LEN;
      f32x4* rowp = (f32x4*)(fill_ptr + (size_t)R * S_LEN);
      const int nl = lw >> 2, nr = (S_LEN - rw) >> 2;
      for (int c = tid; c < nl; c += 256)
        __builtin_nontemporal_store(neg, rowp + c);
      f32x4* rowr = rowp + (rw >> 2);
      for (int c = tid; c < nr; c += 256)
        __builtin_nontemporal_store(neg, rowr + c);
    }
    return;
  }

  const int lane = tid & 63, wave = tid >> 6;
  const int lr = lane & 15, lg = lane >> 4;
  const int bx = b % grid_x, by = b / grid_x;
  const int m0 = by * BM, n0 = bx * BN;
  const int wm = (wave >> 1) * (BM / 2), wn = (wave & 1) * (BN / 2);
  constexpr int MI = BM / 32, NJ = BN / 32;

  f32x4 acc[MI][NJ];
#pragma unroll
  for (int i = 0; i < MI; ++i)
#pragma unroll
    for (int j = 0; j < NJ; ++j) acc[i][j] = (f32x4){0.f, 0.f, 0.f, 0.f};

  for (int kt = 0; kt < K; kt += 64) {
#pragma unroll
    for (int it = 0; it < BM / 32; ++it) {
      int f = it * 256 + tid;
      int row = f >> 3, ch = f & 7;
      int sch = ch ^ (row & 7);  // inverse-swizzle the global SOURCE
      async16(A + (size_t)(m0 + row) * K + kt + sch * 8,
              &As[(it * 256 + wave * 64) * 8]);
    }
#pragma unroll
    for (int it = 0; it < BN / 32; ++it) {
      int f = it * 256 + tid;
      int row = f >> 3, ch = f & 7;
      int sch = ch ^ (row & 7);
      async16(B + (size_t)(n0 + row) * K + kt + sch * 8,
              &Bs[(it * 256 + wave * 64) * 8]);
    }
    __syncthreads();
#pragma unroll
    for (int kk = 0; kk < 2; ++kk) {
      short8 af[MI], bfr[NJ];
      int ca = kk * 4 + lg;
#pragma unroll
      for (int t = 0; t < MI; ++t) {
        int ra = wm + t * 16 + lr;
        af[t] = *(const short8*)&As[ra * 64 + ((ca ^ (ra & 7)) << 3)];
      }
#pragma unroll
      for (int t = 0; t < NJ; ++t) {
        int rb = wn + t * 16 + lr;
        bfr[t] = *(const short8*)&Bs[rb * 64 + ((ca ^ (rb & 7)) << 3)];
      }
#pragma unroll
      for (int i = 0; i < MI; ++i)
#pragma unroll
        for (int j = 0; j < NJ; ++j)
          acc[i][j] = __builtin_amdgcn_mfma_f32_16x16x32_bf16(af[i], bfr[j],
                                                              acc[i][j], 0, 0, 0);
    }
    __syncthreads();
  }
  // epilogue: D layout col=lane&15, row=(lane>>4)*4+reg
#pragma unroll
  for (int j = 0; j < NJ; ++j) {
    int col = n0 + wn + j * 16 + lr;
    float bv = bias[col];
#pragma unroll
    for (int i = 0; i < MI; ++i) {
#pragma unroll
      for (int r = 0; r < 4; ++r) {
        int row = m0 + wm + i * 16 + lg * 4 + r;
        float v = acc[i][j][r] + bv;
        if (OUT_BF16)
          ((u16*)Cout)[(size_t)row * N + col] = f2bf(v);
        else
          ((float*)Cout)[(size_t)row * N + col] = v;
      }
    }
  }
}

// ---------------- fused banded attention (band window writes only) ----
// grid: (32 query-tiles of 64, 16 heads), 256 threads (4 waves).
// Wave w owns query rows [i0+16w, i0+16w+16). Key window: [i0-64, i0+128).
__global__ __launch_bounds__(256, 2) void attn_kernel(
    const u16* __restrict__ qkv,   // [2048][3072] bf16
    float* __restrict__ scores,    // [16][2048][2048] fp32
    u16* __restrict__ ctx) {       // [2048][1024] bf16
  const int h = blockIdx.y;
  const int i0 = blockIdx.x * 64;
  const int j0 = i0 - 64;
  const int tid = threadIdx.x;
  const int lane = tid & 63, wave = tid >> 6;
  const int lr = lane & 15, lg = lane >> 4;

  __shared__ u16 Kl[192 * 72];   // K tile, stride 72 -> 2-way conflicts max
  __shared__ u16 Vt[64 * 200];   // V^T tile [d][jr]
  __shared__ u16 Pl[64 * 200];   // probs bf16 [qi][jr]

  // ---- stage K and V^T (zero-fill out-of-range keys) ----
#pragma unroll
  for (int it = 0; it < 6; ++it) {
    int f = it * 256 + tid;      // 0..1535
    int jr = f >> 3, ch = f & 7;
    int j = j0 + jr;
    short8 kv = {0, 0, 0, 0, 0, 0, 0, 0};
    short8 vv = {0, 0, 0, 0, 0, 0, 0, 0};
    if ((unsigned)j < 2048u) {
      kv = *(const short8*)(qkv + (size_t)j * 3072 + 1024 + h * 64 + ch * 8);
      vv = *(const short8*)(qkv + (size_t)j * 3072 + 2048 + h * 64 + ch * 8);
    }
    *(short4v*)&Kl[jr * 72 + ch * 8] = __builtin_shufflevector(kv, kv, 0, 1, 2, 3);
    *(short4v*)&Kl[jr * 72 + ch * 8 + 4] = __builtin_shufflevector(kv, kv, 4, 5, 6, 7);
#pragma unroll
    for (int e = 0; e < 8; ++e) Vt[(ch * 8 + e) * 200 + jr] = (u16)(short)vv[e];
  }
  __syncthreads();

  // ---- Q fragments straight from global (L2-hot) ----
  short8 qf[2];
#pragma unroll
  for (int kk = 0; kk < 2; ++kk)
    qf[kk] = *(const short8*)(qkv + (size_t)(i0 + wave * 16 + lr) * 3072 +
                              h * 64 + kk * 32 + lg * 8);

  // ---- QK^T: 12 col-tiles of 16, 2 k-substeps ----
  f32x4 sa[12];
#pragma unroll
  for (int n = 0; n < 12; ++n) sa[n] = (f32x4){0.f, 0.f, 0.f, 0.f};
#pragma unroll
  for (int kk = 0; kk < 2; ++kk) {
    short8 a = qf[kk];
#pragma unroll
    for (int nt = 0; nt < 12; ++nt) {
      int jr = nt * 16 + lr;
      int d = kk * 32 + lg * 8;
      short4v lo = *(const short4v*)&Kl[jr * 72 + d];
      short4v hi = *(const short4v*)&Kl[jr * 72 + d + 4];
      short8 b = __builtin_shufflevector(lo, hi, 0, 1, 2, 3, 4, 5, 6, 7);
      sa[nt] = __builtin_amdgcn_mfma_f32_16x16x32_bf16(a, b, sa[nt], 0, 0, 0);
    }
  }

  // ---- scale + band mask (in place) ----
  const float scale = 0.125f;  // DH^-0.5
#pragma unroll
  for (int nt = 0; nt < 12; ++nt) {
    int j = j0 + nt * 16 + lr;
#pragma unroll
    for (int r = 0; r < 4; ++r) {
      int i = i0 + wave * 16 + lg * 4 + r;
      bool inb = (j >= i - 64) && (j <= i + 64);
      sa[nt][r] = inb ? sa[nt][r] * scale : NEGM;
    }
  }

  // ---- write the valid window (cached scalar stores) ----
  float* srow_base = scores + (size_t)h * 2048 * 2048;
#pragma unroll
  for (int r = 0; r < 4; ++r) {
    int i = i0 + wave * 16 + lg * 4 + r;
    float* rowp = srow_base + (size_t)i * 2048;
#pragma unroll
    for (int nt = 0; nt < 12; ++nt) {
      int j = j0 + nt * 16 + lr;
      if ((unsigned)j < 2048u) rowp[j] = sa[nt][r];
    }
  }

  // ---- softmax per row (16-lane group holds a full 192-col row) ----
#pragma unroll
  for (int r = 0; r < 4; ++r) {
    float m = sa[0][r];
#pragma unroll
    for (int nt = 1; nt < 12; ++nt) m = fmaxf(m, sa[nt][r]);
#pragma unroll
    for (int off = 1; off < 16; off <<= 1) m = fmaxf(m, __shfl_xor(m, off));
    float p[12], s = 0.f;
#pragma unroll
    for (int nt = 0; nt < 12; ++nt) {
      p[nt] = __expf(sa[nt][r] - m);  // masked -> 0
      s += p[nt];
    }
#pragma unroll
    for (int off = 1; off < 16; off <<= 1) s += __shfl_xor(s, off);
    float inv = 1.f / s;
    int row = wave * 16 + lg * 4 + r;
#pragma unroll
    for (int nt = 0; nt < 12; ++nt)
      Pl[row * 200 + nt * 16 + lr] = f2bf(p[nt] * inv);
  }
  __syncthreads();

  // ---- PV: ctx[64][64] = P[64][192] @ V[192][64] ----
  f32x4 ca[4];
#pragma unroll
  for (int d = 0; d < 4; ++d) ca[d] = (f32x4){0.f, 0.f, 0.f, 0.f};
#pragma unroll
  for (int kk = 0; kk < 6; ++kk) {
    short8 a = *(const short8*)&Pl[(wave * 16 + lr) * 200 + kk * 32 + lg * 8];
#pragma unroll
    for (int dt = 0; dt < 4; ++dt) {
      short8 b = *(const short8*)&Vt[(dt * 16 + lr) * 200 + kk * 32 + lg * 8];
      ca[dt] = __builtin_amdgcn_mfma_f32_16x16x32_bf16(a, b, ca[dt], 0, 0, 0);
    }
  }
#pragma unroll
  for (int dt = 0; dt < 4; ++dt)
#pragma unroll
    for (int r = 0; r < 4; ++r) {
      int i = i0 + wave * 16 + lg * 4 + r;
      int d = h * 64 + dt * 16 + lr;
      ctx[(size_t)i * 1024 + d] = f2bf(ca[dt][r]);
    }
}

// ---------------- launcher ----------------
extern "C" void kernel_launch(void* const* d_in, const int* in_sizes, int n_in,
                              void* d_out, int out_size, void* d_ws, size_t ws_size,
                              hipStream_t stream) {
  const float* x    = (const float*)d_in[0];
  const float* Wqkv = (const float*)d_in[1];
  const float* bqkv = (const float*)d_in[2];
  const float* Wout = (const float*)d_in[3];
  const float* bout = (const float*)d_in[4];

  float* out    = (float*)d_out;
  float* scores = out + (size_t)S_LEN * EMB;

  char* ws = (char*)d_ws;
  u16* x_bf    = (u16*)(ws);
  u16* wqkv_bf = (u16*)(ws + (4u << 20));
  u16* wout_bf = (u16*)(ws + (10u << 20));
  u16* qkv_bf  = (u16*)(ws + (12u << 20));
  u16* ctx_bf  = (u16*)(ws + (24u << 20));

  const int n1 = S_LEN * EMB;       // x
  const int n2 = 3 * EMB * EMB;     // W_qkv
  const int n3 = EMB * EMB;         // W_out

  // all three casts in one launch
  cast3_kernel<<<(n1 + n2 + n3) / 8 / 256, 256, 0, stream>>>(
      x, x_bf, n1, Wqkv, wqkv_bf, n2, Wout, wout_bf, n3);

  // qkv = x @ Wqkv^T + b (bf16 out). 128x96 tiles -> 512 blocks = 2/CU
  // (balanced), co-launched with complement fill of rows [0, RSPLIT).
  // 512 + 256 = 768 blocks = 3/CU.
  gemm_kernel<128, 96, 1, 3><<<768, 256, 0, stream>>>(
      x_bf, wqkv_bf, bqkv, qkv_bf, S_LEN, 3 * EMB, EMB,
      /*grid_x=*/3 * EMB / 96, /*gemm_blocks=*/512,
      scores, /*fr0=*/0, /*fr1=*/RSPLIT, /*fill_blocks=*/256);

  // banded attention: writes band window + ctx
  attn_kernel<<<dim3(S_LEN / 64, NH), 256, 0, stream>>>(qkv_bf, scores, ctx_bf);

  // out = ctx @ Wout^T + b (fp32 out); 64x64 tiles -> 512 blocks (2/CU),
  // co-launched with complement fill of rows [RSPLIT, 32768).
  gemm_kernel<64, 64, 0, 3><<<768, 256, 0, stream>>>(
      ctx_bf, wout_bf, bout, out, S_LEN, EMB, EMB,
      /*grid_x=*/EMB / 64, /*gemm_blocks=*/512,
      scores, /*fr0=*/RSPLIT, /*fr1=*/NROWS, /*fill_blocks=*/256);
}